// Round 1
// baseline (971.102 us; speedup 1.0000x reference)
//
#include <hip/hip_runtime.h>

#define N_NODES 100000
#define E_HALF  500000
#define E_TOT   1000000
#define NFEAT   128
#define NHID    64
#define NCLS    40
#define SCAN_T  1024
#define SCAN_NB 98   // ceil(N_NODES/1024)

// ---------------- node norms ----------------
template<int D>
__global__ __launch_bounds__(256) void row_norm_k(const float* __restrict__ x, float* __restrict__ nrm) {
    int w = (blockIdx.x * 256 + threadIdx.x) >> 6;
    int lane = threadIdx.x & 63;
    if (w >= N_NODES) return;
    const float* row = x + (size_t)w * D;
    float s = 0.f;
#pragma unroll
    for (int i = 0; i < D / 64; ++i) { float v = row[lane + 64 * i]; s = fmaf(v, v, s); }
#pragma unroll
    for (int off = 32; off; off >>= 1) s += __shfl_xor(s, off);
    if (lane == 0) nrm[w] = sqrtf(s);
}

// ---------------- cosine sim on edge pairs (16 lanes / undirected pair) ----------------
template<int D, bool MASKED>
__global__ __launch_bounds__(256) void sim_k(const float* __restrict__ f, const float* __restrict__ nrm,
                                             const int* __restrict__ src, const int* __restrict__ dst,
                                             const int* __restrict__ rev, const float* __restrict__ we_mask,
                                             float* __restrict__ sim, float* __restrict__ rowsum) {
    int g = blockIdx.x * 256 + threadIdx.x;
    int ep = g >> 4, sl = g & 15;
    if (ep >= E_HALF) return;
    int s = src[ep], d = dst[ep];
    const float* fa = f + (size_t)s * D + sl * (D / 16);
    const float* fb = f + (size_t)d * D + sl * (D / 16);
    float acc = 0.f;
#pragma unroll
    for (int i = 0; i < D / 16; i += 4) {
        float4 va = *(const float4*)(fa + i);
        float4 vb = *(const float4*)(fb + i);
        acc = fmaf(va.x, vb.x, acc); acc = fmaf(va.y, vb.y, acc);
        acc = fmaf(va.z, vb.z, acc); acc = fmaf(va.w, vb.w, acc);
    }
    acc += __shfl_xor(acc, 8); acc += __shfl_xor(acc, 4);
    acc += __shfl_xor(acc, 2); acc += __shfl_xor(acc, 1);
    if (sl == 0) {
        int r = rev[ep];
        float na = nrm[s]; na = (na == 0.f) ? 1.f : na;
        float nb = nrm[d]; nb = (nb == 0.f) ? 1.f : nb;
        float c = acc / (na * nb);
        float t = (c < 0.1f) ? 0.f : c;      // t >= 0 always
        float se = t, sr = t;
        if (MASKED) {
            se = (we_mask[ep] > 0.f) ? t : 0.f;
            sr = (we_mask[r]  > 0.f) ? t : 0.f;
        }
        sim[ep] = se;
        sim[r]  = sr;
        if (se > 0.f) atomicAdd(&rowsum[s], se);
        if (sr > 0.f) atomicAdd(&rowsum[d], sr);
    }
}

// ---------------- L1 row-normalize (in place) ----------------
__global__ __launch_bounds__(256) void a_k(float* __restrict__ a, const float* __restrict__ rowsum,
                                           const int* __restrict__ src) {
    int e = blockIdx.x * 256 + threadIdx.x;
    if (e >= E_TOT) return;
    float rs = rowsum[src[e]];
    rs = (rs == 0.f) ? 1.f : rs;
    a[e] = a[e] / rs;
}

// ---------------- learnable keep/drop + w_e + att-deg + gcn-deg atomics ----------------
__global__ __launch_bounds__(256) void keep_k(const float* __restrict__ a, const int* __restrict__ rev,
                                              const int* __restrict__ src, const int* __restrict__ dst,
                                              const float* __restrict__ Wd, const float* __restrict__ bd,
                                              float* __restrict__ we, float* __restrict__ deg,
                                              float* __restrict__ degc) {
    int e = blockIdx.x * 256 + threadIdx.x;
    if (e >= E_TOT) return;
    float ae = a[e], ar = a[rev[e]];
    float z = ae * Wd[0] + ar * Wd[1] + bd[0];
    float av = (z > 0.f) ? ae : 0.f;          // sigmoid(z)>0.5 <=> z>0
    float w = (av > 0.f) ? expf(av) : 0.f;
    we[e] = w;
    if (av != 0.f) atomicAdd(&deg[src[e]], 1.f);
    if (w  != 0.f) atomicAdd(&degc[dst[e]], w);
}

// ---------------- per-node: w_s = exp(1/(deg+1)); dis = (degc + w_s + 1)^-1/2 ----------------
__global__ __launch_bounds__(256) void node_k(const float* __restrict__ deg, float* __restrict__ w_s,
                                              const float* __restrict__ degc, float* __restrict__ dis) {
    int i = blockIdx.x * 256 + threadIdx.x;
    if (i >= N_NODES) return;
    float ws = expf(1.f / (deg[i] + 1.f));
    w_s[i] = ws;
    float dg = degc[i] + ws + 1.f;
    dis[i] = (dg > 0.f) ? 1.f / sqrtf(dg) : 0.f;
}

// ---------------- CSR build ----------------
__global__ __launch_bounds__(256) void count_k(const int* __restrict__ dst, int* __restrict__ cnt) {
    int e = blockIdx.x * 256 + threadIdx.x;
    if (e < E_TOT) atomicAdd(&cnt[dst[e]], 1);
}

__global__ __launch_bounds__(1024) void scan1_k(const int* __restrict__ cnt, int* __restrict__ bsum) {
    int i = blockIdx.x * SCAN_T + threadIdx.x;
    int v = (i < N_NODES) ? cnt[i] : 0;
#pragma unroll
    for (int off = 32; off; off >>= 1) v += __shfl_xor(v, off);
    __shared__ int wsm[16];
    int lane = threadIdx.x & 63, wid = threadIdx.x >> 6;
    if (lane == 0) wsm[wid] = v;
    __syncthreads();
    if (threadIdx.x == 0) {
        int s = 0;
#pragma unroll
        for (int k = 0; k < 16; ++k) s += wsm[k];
        bsum[blockIdx.x] = s;
    }
}

__global__ __launch_bounds__(128) void scan2_k(int* __restrict__ bsum) {
    __shared__ int tmp[128];
    int t = threadIdx.x;
    int v = (t < SCAN_NB) ? bsum[t] : 0;
    tmp[t] = v;
    __syncthreads();
    for (int off = 1; off < 128; off <<= 1) {
        int add = (t >= off) ? tmp[t - off] : 0;
        __syncthreads();
        tmp[t] += add;
        __syncthreads();
    }
    if (t < SCAN_NB) bsum[t] = (t > 0) ? tmp[t - 1] : 0;
}

__global__ __launch_bounds__(1024) void scan3_k(const int* __restrict__ cnt, const int* __restrict__ bsum,
                                                int* __restrict__ row_start) {
    int i = blockIdx.x * SCAN_T + threadIdx.x;
    int v = (i < N_NODES) ? cnt[i] : 0;
    int lane = threadIdx.x & 63, wid = threadIdx.x >> 6;
    int x = v;
#pragma unroll
    for (int off = 1; off < 64; off <<= 1) {
        int y = __shfl_up(x, off);
        if (lane >= off) x += y;
    }
    __shared__ int wsum[16], woff[16];
    if (lane == 63) wsum[wid] = x;
    __syncthreads();
    if (threadIdx.x == 0) {
        int s = 0;
#pragma unroll
        for (int k = 0; k < 16; ++k) { woff[k] = s; s += wsum[k]; }
    }
    __syncthreads();
    int excl = (x - v) + woff[wid] + bsum[blockIdx.x];
    if (i < N_NODES) row_start[i] = excl;
    if (i == N_NODES - 1) row_start[N_NODES] = excl + v;
}

__global__ __launch_bounds__(256) void fill_k(const int* __restrict__ src, const int* __restrict__ dst,
                                              const int* __restrict__ row_start, int* __restrict__ cursor,
                                              int* __restrict__ csr_src, int* __restrict__ csr_eid) {
    int e = blockIdx.x * 256 + threadIdx.x;
    if (e >= E_TOT) return;
    int d = dst[e];
    int p = atomicAdd(&cursor[d], 1);
    int slot = row_start[d] + p;
    csr_src[slot] = src[e];
    csr_eid[slot] = e;
}

// ---------------- per-slot weight = dis[src] * w_e[eid] ----------------
__global__ __launch_bounds__(256) void slotw_k(const int* __restrict__ csr_src, const int* __restrict__ csr_eid,
                                               const float* __restrict__ we, const float* __restrict__ dis,
                                               float* __restrict__ wsl) {
    int t = blockIdx.x * 256 + threadIdx.x;
    if (t >= E_TOT) return;
    wsl[t] = dis[csr_src[t]] * we[csr_eid[t]];
}

// ---------------- GEMM1: x[N,128] @ W1[128,64] ----------------
__global__ __launch_bounds__(256) void gemm1_k(const float* __restrict__ X, const float* __restrict__ W,
                                               float* __restrict__ Y) {
    __shared__ float sXT[8][128];
    __shared__ float sW[8][64];
    int tid = threadIdx.x;
    int row0 = blockIdx.x * 128;
    int tc = tid & 15;
    int tr = tid >> 4;
    float acc[8][4] = {};
    int lrow = tid >> 1, lhalf = tid & 1;
    int grow = row0 + lrow;
    for (int k0 = 0; k0 < NFEAT; k0 += 8) {
        float4 v = make_float4(0.f, 0.f, 0.f, 0.f);
        if (grow < N_NODES) v = *(const float4*)(X + (size_t)grow * NFEAT + k0 + lhalf * 4);
        sXT[lhalf * 4 + 0][lrow] = v.x;
        sXT[lhalf * 4 + 1][lrow] = v.y;
        sXT[lhalf * 4 + 2][lrow] = v.z;
        sXT[lhalf * 4 + 3][lrow] = v.w;
        float2 wv2 = *(const float2*)(W + (size_t)(k0 + (tid >> 5)) * NHID + (tid & 31) * 2);
        *(float2*)&sW[tid >> 5][(tid & 31) * 2] = wv2;
        __syncthreads();
#pragma unroll
        for (int k = 0; k < 8; ++k) {
            float4 xa = *(const float4*)&sXT[k][tr * 8];
            float4 xb = *(const float4*)&sXT[k][tr * 8 + 4];
            float4 wv = *(const float4*)&sW[k][tc * 4];
            float xr[8] = {xa.x, xa.y, xa.z, xa.w, xb.x, xb.y, xb.z, xb.w};
            float wr[4] = {wv.x, wv.y, wv.z, wv.w};
#pragma unroll
            for (int i = 0; i < 8; ++i)
#pragma unroll
                for (int jj = 0; jj < 4; ++jj)
                    acc[i][jj] = fmaf(xr[i], wr[jj], acc[i][jj]);
        }
        __syncthreads();
    }
#pragma unroll
    for (int i = 0; i < 8; ++i) {
        int r = row0 + tr * 8 + i;
        if (r < N_NODES)
            *(float4*)(Y + (size_t)r * NHID + tc * 4) =
                make_float4(acc[i][0], acc[i][1], acc[i][2], acc[i][3]);
    }
}

// ---------------- GEMM2: h[N,64] @ W2[64,40] ----------------
__global__ __launch_bounds__(256) void gemm2_k(const float* __restrict__ X, const float* __restrict__ W,
                                               float* __restrict__ Y) {
    __shared__ float sXT[8][128];
    __shared__ float sW[320];
    int tid = threadIdx.x;
    int row0 = blockIdx.x * 128;
    int tc = tid & 7;
    int tr = tid >> 3;
    float acc[4][5] = {};
    int lrow = tid >> 1, lhalf = tid & 1;
    int grow = row0 + lrow;
    for (int k0 = 0; k0 < NHID; k0 += 8) {
        float4 v = make_float4(0.f, 0.f, 0.f, 0.f);
        if (grow < N_NODES) v = *(const float4*)(X + (size_t)grow * NHID + k0 + lhalf * 4);
        sXT[lhalf * 4 + 0][lrow] = v.x;
        sXT[lhalf * 4 + 1][lrow] = v.y;
        sXT[lhalf * 4 + 2][lrow] = v.z;
        sXT[lhalf * 4 + 3][lrow] = v.w;
        if (tid < 160) {
            float2 w2 = *(const float2*)(W + k0 * NCLS + tid * 2);
            sW[tid * 2] = w2.x; sW[tid * 2 + 1] = w2.y;
        }
        __syncthreads();
#pragma unroll
        for (int k = 0; k < 8; ++k) {
            float4 xv = *(const float4*)&sXT[k][tr * 4];
            float xr[4] = {xv.x, xv.y, xv.z, xv.w};
            float wr[5];
#pragma unroll
            for (int jj = 0; jj < 5; ++jj) wr[jj] = sW[k * NCLS + tc * 5 + jj];
#pragma unroll
            for (int i = 0; i < 4; ++i)
#pragma unroll
                for (int jj = 0; jj < 5; ++jj)
                    acc[i][jj] = fmaf(xr[i], wr[jj], acc[i][jj]);
        }
        __syncthreads();
    }
#pragma unroll
    for (int i = 0; i < 4; ++i) {
        int r = row0 + tr * 4 + i;
        if (r < N_NODES) {
#pragma unroll
            for (int jj = 0; jj < 5; ++jj) Y[(size_t)r * NCLS + tc * 5 + jj] = acc[i][jj];
        }
    }
}

// ---------------- aggregation layer 1 (wave per node, +bias, relu) ----------------
__global__ __launch_bounds__(256) void agg1_k(const float* __restrict__ hpre, const int* __restrict__ row_start,
                                              const int* __restrict__ csr_src, const float* __restrict__ wsl,
                                              const float* __restrict__ dis, const float* __restrict__ w_s,
                                              const float* __restrict__ b, float* __restrict__ h) {
    int j = (blockIdx.x * 256 + threadIdx.x) >> 6;
    int lane = threadIdx.x & 63;
    if (j >= N_NODES) return;
    int e0 = row_start[j], e1 = row_start[j + 1];
    float acc = 0.f;
    for (int t = e0; t < e1; ++t) {
        int s = csr_src[t];
        float w = wsl[t];
        if (w != 0.f) acc = fmaf(w, hpre[(size_t)s * NHID + lane], acc);
    }
    float dj = dis[j];
    acc = fmaf(dj * (w_s[j] + 1.f), hpre[(size_t)j * NHID + lane], acc);
    float v = fmaf(acc, dj, b[lane]);
    h[(size_t)j * NHID + lane] = fmaxf(v, 0.f);
}

// ---------------- aggregation layer 2 + log_softmax (wave per node) ----------------
__global__ __launch_bounds__(256) void agg2_k(const float* __restrict__ hp2, const int* __restrict__ row_start,
                                              const int* __restrict__ csr_src, const float* __restrict__ wsl,
                                              const float* __restrict__ dis, const float* __restrict__ w_s,
                                              const float* __restrict__ b, float* __restrict__ out) {
    int j = (blockIdx.x * 256 + threadIdx.x) >> 6;
    int lane = threadIdx.x & 63;
    if (j >= N_NODES) return;
    int e0 = row_start[j], e1 = row_start[j + 1];
    float acc = 0.f;
    for (int t = e0; t < e1; ++t) {
        int s = csr_src[t];
        float w = wsl[t];
        if (w != 0.f && lane < NCLS) acc = fmaf(w, hp2[(size_t)s * NCLS + lane], acc);
    }
    float dj = dis[j];
    float v = -1e30f;
    if (lane < NCLS) {
        acc = fmaf(dj * (w_s[j] + 1.f), hp2[(size_t)j * NCLS + lane], acc);
        v = fmaf(acc, dj, b[lane]);
    }
    float m = v;
#pragma unroll
    for (int off = 32; off; off >>= 1) m = fmaxf(m, __shfl_xor(m, off));
    float ex = (lane < NCLS) ? expf(v - m) : 0.f;
    float ssum = ex;
#pragma unroll
    for (int off = 32; off; off >>= 1) ssum += __shfl_xor(ssum, off);
    if (lane < NCLS) out[(size_t)j * NCLS + lane] = v - m - logf(ssum);
}

extern "C" void kernel_launch(void* const* d_in, const int* in_sizes, int n_in,
                              void* d_out, int out_size, void* d_ws, size_t ws_size,
                              hipStream_t stream) {
    (void)in_sizes; (void)n_in; (void)out_size; (void)ws_size;
    const float* x  = (const float*)d_in[0];
    const int*   src = (const int*)d_in[1];
    const int*   dst = (const int*)d_in[2];
    const int*   rev = (const int*)d_in[3];
    const float* W1 = (const float*)d_in[4];
    const float* b1 = (const float*)d_in[5];
    const float* W2 = (const float*)d_in[6];
    const float* b2 = (const float*)d_in[7];
    const float* Wd = (const float*)d_in[8];
    const float* bd = (const float*)d_in[9];
    float* out = (float*)d_out;

    char* ws = (char*)d_ws;
    size_t off = 0;
    auto alloc = [&](size_t bytes) -> void* {
        void* p = ws + off;
        off = (off + bytes + 255) & ~(size_t)255;
        return p;
    };
    size_t zg0 = off;
    float* rowsum = (float*)alloc((size_t)N_NODES * 4);
    float* deg    = (float*)alloc((size_t)N_NODES * 4);
    float* degc   = (float*)alloc((size_t)N_NODES * 4);
    size_t zg0_end = off;            // pass-2 re-zero: rowsum..degc
    int*   cnt    = (int*)alloc((size_t)N_NODES * 4);   // doubles as cursor
    size_t zg1_end = off;            // initial zero: rowsum..cnt
    float* nrm  = (float*)alloc((size_t)N_NODES * 4);
    float* w_s  = (float*)alloc((size_t)N_NODES * 4);
    float* dis  = (float*)alloc((size_t)N_NODES * 4);
    float* abuf = (float*)alloc((size_t)E_TOT * 4);
    float* we1  = (float*)alloc((size_t)E_TOT * 4);
    float* we2  = (float*)alloc((size_t)E_TOT * 4);
    float* wsl  = (float*)alloc((size_t)E_TOT * 4);
    float* hpre = (float*)alloc((size_t)N_NODES * NHID * 4);
    float* h    = (float*)alloc((size_t)N_NODES * NHID * 4);
    int* row_start = (int*)alloc((size_t)(N_NODES + 1) * 4);
    int* csr_src   = (int*)alloc((size_t)E_TOT * 4);
    int* csr_eid   = (int*)alloc((size_t)E_TOT * 4);
    int* bsum      = (int*)alloc(256 * 4);

    const int BE = (E_TOT + 255) / 256;
    const int BN = (N_NODES + 255) / 256;
    const int BW = (N_NODES * 64 + 255) / 256;
    const int BS = (E_HALF * 16 + 255) / 256;
    const int BG = (N_NODES + 127) / 128;

    hipMemsetAsync(ws + zg0, 0, zg1_end - zg0, stream);   // rowsum,deg,degc,cnt

    // CSR (topology shared by both layers)
    count_k<<<BE, 256, 0, stream>>>(dst, cnt);
    scan1_k<<<SCAN_NB, 1024, 0, stream>>>(cnt, bsum);
    scan2_k<<<1, 128, 0, stream>>>(bsum);
    scan3_k<<<SCAN_NB, 1024, 0, stream>>>(cnt, bsum, row_start);
    hipMemsetAsync(cnt, 0, (size_t)N_NODES * 4, stream);  // reuse as cursor
    fill_k<<<BE, 256, 0, stream>>>(src, dst, row_start, cnt, csr_src, csr_eid);

    // ---- pass 1: attention on raw features ----
    row_norm_k<NFEAT><<<BW, 256, 0, stream>>>(x, nrm);
    sim_k<NFEAT, false><<<BS, 256, 0, stream>>>(x, nrm, src, dst, rev, nullptr, abuf, rowsum);
    a_k<<<BE, 256, 0, stream>>>(abuf, rowsum, src);
    keep_k<<<BE, 256, 0, stream>>>(abuf, rev, src, dst, Wd, bd, we1, deg, degc);
    node_k<<<BN, 256, 0, stream>>>(deg, w_s, degc, dis);
    gemm1_k<<<BG, 256, 0, stream>>>(x, W1, hpre);
    slotw_k<<<BE, 256, 0, stream>>>(csr_src, csr_eid, we1, dis, wsl);
    agg1_k<<<BW, 256, 0, stream>>>(hpre, row_start, csr_src, wsl, dis, w_s, b1, h);

    // ---- pass 2: attention on hidden features ----
    hipMemsetAsync(ws + zg0, 0, zg0_end - zg0, stream);   // rowsum,deg,degc
    row_norm_k<NHID><<<BW, 256, 0, stream>>>(h, nrm);
    sim_k<NHID, true><<<BS, 256, 0, stream>>>(h, nrm, src, dst, rev, we1, abuf, rowsum);
    a_k<<<BE, 256, 0, stream>>>(abuf, rowsum, src);
    keep_k<<<BE, 256, 0, stream>>>(abuf, rev, src, dst, Wd, bd, we2, deg, degc);
    node_k<<<BN, 256, 0, stream>>>(deg, w_s, degc, dis);
    gemm2_k<<<BG, 256, 0, stream>>>(h, W2, hpre);         // hpre reused as [N,40]
    slotw_k<<<BE, 256, 0, stream>>>(csr_src, csr_eid, we2, dis, wsl);
    agg2_k<<<BW, 256, 0, stream>>>(hpre, row_start, csr_src, wsl, dis, w_s, b2, out);
}

// Round 2
// 788.656 us; speedup vs baseline: 1.2313x; 1.2313x over previous
//
#include <hip/hip_runtime.h>

#define N_NODES 100000
#define E_HALF  500000
#define E_TOT   1000000
#define NFEAT   128
#define NHID    64
#define NCLS    40
#define SCAN_T  1024
#define SCAN_NB 98   // ceil(N_NODES/1024)

// ---------------- node norms ----------------
template<int D>
__global__ __launch_bounds__(256) void row_norm_k(const float* __restrict__ x, float* __restrict__ nrm) {
    int w = (blockIdx.x * 256 + threadIdx.x) >> 6;
    int lane = threadIdx.x & 63;
    if (w >= N_NODES) return;
    const float* row = x + (size_t)w * D;
    float s = 0.f;
#pragma unroll
    for (int i = 0; i < D / 64; ++i) { float v = row[lane + 64 * i]; s = fmaf(v, v, s); }
#pragma unroll
    for (int off = 32; off; off >>= 1) s += __shfl_xor(s, off);
    if (lane == 0) nrm[w] = sqrtf(s);
}

// ---------------- cosine sim on edge pairs (16 lanes / undirected pair) ----------------
template<int D, bool MASKED>
__global__ __launch_bounds__(256) void sim_k(const float* __restrict__ f, const float* __restrict__ nrm,
                                             const int* __restrict__ src, const int* __restrict__ dst,
                                             const int* __restrict__ rev, const float* __restrict__ we_mask,
                                             float* __restrict__ sim, float* __restrict__ rowsum) {
    int g = blockIdx.x * 256 + threadIdx.x;
    int ep = g >> 4, sl = g & 15;
    if (ep >= E_HALF) return;
    int r = rev[ep];
    bool m0 = true, m1 = true;
    if (MASKED) {
        m0 = we_mask[ep] > 0.f;
        m1 = we_mask[r]  > 0.f;
        if (!m0 && !m1) {               // both directions dropped in pass 1: skip the row gathers
            if (sl == 0) { sim[ep] = 0.f; sim[r] = 0.f; }
            return;
        }
    }
    int s = src[ep], d = dst[ep];
    const float* fa = f + (size_t)s * D + sl * (D / 16);
    const float* fb = f + (size_t)d * D + sl * (D / 16);
    float acc = 0.f;
#pragma unroll
    for (int i = 0; i < D / 16; i += 4) {
        float4 va = *(const float4*)(fa + i);
        float4 vb = *(const float4*)(fb + i);
        acc = fmaf(va.x, vb.x, acc); acc = fmaf(va.y, vb.y, acc);
        acc = fmaf(va.z, vb.z, acc); acc = fmaf(va.w, vb.w, acc);
    }
    acc += __shfl_xor(acc, 8); acc += __shfl_xor(acc, 4);
    acc += __shfl_xor(acc, 2); acc += __shfl_xor(acc, 1);
    if (sl == 0) {
        float na = nrm[s]; na = (na == 0.f) ? 1.f : na;
        float nb = nrm[d]; nb = (nb == 0.f) ? 1.f : nb;
        float c = acc / (na * nb);
        float t = (c < 0.1f) ? 0.f : c;      // t >= 0 always
        float se = m0 ? t : 0.f;
        float sr = m1 ? t : 0.f;
        sim[ep] = se;
        sim[r]  = sr;
        if (se > 0.f) atomicAdd(&rowsum[s], se);
        if (sr > 0.f) atomicAdd(&rowsum[d], sr);
    }
}

// ---------------- fused L1-normalize + learnable keep/drop + w_e + deg atomics ----------------
__global__ __launch_bounds__(256) void keep_k(const float* __restrict__ sim, const int* __restrict__ rev,
                                              const int* __restrict__ src, const int* __restrict__ dst,
                                              const float* __restrict__ rowsum,
                                              const float* __restrict__ Wd, const float* __restrict__ bd,
                                              float* __restrict__ we, float* __restrict__ deg,
                                              float* __restrict__ degc) {
    int e = blockIdx.x * 256 + threadIdx.x;
    if (e >= E_TOT) return;
    int s = src[e], d = dst[e];
    float rs = rowsum[s]; rs = (rs == 0.f) ? 1.f : rs;
    float rd = rowsum[d]; rd = (rd == 0.f) ? 1.f : rd;      // src[rev[e]] == dst[e]
    float ae = sim[e] / rs;
    float ar = sim[rev[e]] / rd;
    float z = ae * Wd[0] + ar * Wd[1] + bd[0];
    float av = (z > 0.f) ? ae : 0.f;          // sigmoid(z)>0.5 <=> z>0
    float w = (av > 0.f) ? expf(av) : 0.f;
    we[e] = w;
    if (av != 0.f) atomicAdd(&deg[s], 1.f);
    if (w  != 0.f) atomicAdd(&degc[d], w);
}

// ---------------- per-node: w_s = exp(1/(deg+1)); dis = (degc + w_s + 1)^-1/2 ----------------
__global__ __launch_bounds__(256) void node_k(const float* __restrict__ deg, float* __restrict__ w_s,
                                              const float* __restrict__ degc, float* __restrict__ dis) {
    int i = blockIdx.x * 256 + threadIdx.x;
    if (i >= N_NODES) return;
    float ws = expf(1.f / (deg[i] + 1.f));
    w_s[i] = ws;
    float dg = degc[i] + ws + 1.f;
    dis[i] = (dg > 0.f) ? 1.f / sqrtf(dg) : 0.f;
}

// ---------------- CSR build ----------------
__global__ __launch_bounds__(256) void count_k(const int* __restrict__ dst, int* __restrict__ cnt) {
    int e = blockIdx.x * 256 + threadIdx.x;
    if (e < E_TOT) atomicAdd(&cnt[dst[e]], 1);
}

__global__ __launch_bounds__(1024) void scan1_k(const int* __restrict__ cnt, int* __restrict__ bsum) {
    int i = blockIdx.x * SCAN_T + threadIdx.x;
    int v = (i < N_NODES) ? cnt[i] : 0;
#pragma unroll
    for (int off = 32; off; off >>= 1) v += __shfl_xor(v, off);
    __shared__ int wsm[16];
    int lane = threadIdx.x & 63, wid = threadIdx.x >> 6;
    if (lane == 0) wsm[wid] = v;
    __syncthreads();
    if (threadIdx.x == 0) {
        int s = 0;
#pragma unroll
        for (int k = 0; k < 16; ++k) s += wsm[k];
        bsum[blockIdx.x] = s;
    }
}

__global__ __launch_bounds__(128) void scan2_k(int* __restrict__ bsum) {
    __shared__ int tmp[128];
    int t = threadIdx.x;
    int v = (t < SCAN_NB) ? bsum[t] : 0;
    tmp[t] = v;
    __syncthreads();
    for (int off = 1; off < 128; off <<= 1) {
        int add = (t >= off) ? tmp[t - off] : 0;
        __syncthreads();
        tmp[t] += add;
        __syncthreads();
    }
    if (t < SCAN_NB) bsum[t] = (t > 0) ? tmp[t - 1] : 0;
}

__global__ __launch_bounds__(1024) void scan3_k(const int* __restrict__ cnt, const int* __restrict__ bsum,
                                                int* __restrict__ row_start) {
    int i = blockIdx.x * SCAN_T + threadIdx.x;
    int v = (i < N_NODES) ? cnt[i] : 0;
    int lane = threadIdx.x & 63, wid = threadIdx.x >> 6;
    int x = v;
#pragma unroll
    for (int off = 1; off < 64; off <<= 1) {
        int y = __shfl_up(x, off);
        if (lane >= off) x += y;
    }
    __shared__ int wsum[16], woff[16];
    if (lane == 63) wsum[wid] = x;
    __syncthreads();
    if (threadIdx.x == 0) {
        int s = 0;
#pragma unroll
        for (int k = 0; k < 16; ++k) { woff[k] = s; s += wsum[k]; }
    }
    __syncthreads();
    int excl = (x - v) + woff[wid] + bsum[blockIdx.x];
    if (i < N_NODES) row_start[i] = excl;
    if (i == N_NODES - 1) row_start[N_NODES] = excl + v;
}

__global__ __launch_bounds__(256) void fill_k(const int* __restrict__ src, const int* __restrict__ dst,
                                              const int* __restrict__ row_start, int* __restrict__ cursor,
                                              int* __restrict__ csr_src, int* __restrict__ csr_eid) {
    int e = blockIdx.x * 256 + threadIdx.x;
    if (e >= E_TOT) return;
    int d = dst[e];
    int p = atomicAdd(&cursor[d], 1);
    int slot = row_start[d] + p;
    csr_src[slot] = src[e];
    csr_eid[slot] = e;
}

// ---------------- per-slot weight = dis[src] * w_e[eid] ----------------
__global__ __launch_bounds__(256) void slotw_k(const int* __restrict__ csr_src, const int* __restrict__ csr_eid,
                                               const float* __restrict__ we, const float* __restrict__ dis,
                                               float* __restrict__ wsl) {
    int t = blockIdx.x * 256 + threadIdx.x;
    if (t >= E_TOT) return;
    wsl[t] = dis[csr_src[t]] * we[csr_eid[t]];
}

// ---------------- GEMM1: x[N,128] @ W1[128,64] ----------------
__global__ __launch_bounds__(256) void gemm1_k(const float* __restrict__ X, const float* __restrict__ W,
                                               float* __restrict__ Y) {
    __shared__ float sXT[8][128];
    __shared__ float sW[8][64];
    int tid = threadIdx.x;
    int row0 = blockIdx.x * 128;
    int tc = tid & 15;
    int tr = tid >> 4;
    float acc[8][4] = {};
    int lrow = tid >> 1, lhalf = tid & 1;
    int grow = row0 + lrow;
    for (int k0 = 0; k0 < NFEAT; k0 += 8) {
        float4 v = make_float4(0.f, 0.f, 0.f, 0.f);
        if (grow < N_NODES) v = *(const float4*)(X + (size_t)grow * NFEAT + k0 + lhalf * 4);
        sXT[lhalf * 4 + 0][lrow] = v.x;
        sXT[lhalf * 4 + 1][lrow] = v.y;
        sXT[lhalf * 4 + 2][lrow] = v.z;
        sXT[lhalf * 4 + 3][lrow] = v.w;
        float2 wv2 = *(const float2*)(W + (size_t)(k0 + (tid >> 5)) * NHID + (tid & 31) * 2);
        *(float2*)&sW[tid >> 5][(tid & 31) * 2] = wv2;
        __syncthreads();
#pragma unroll
        for (int k = 0; k < 8; ++k) {
            float4 xa = *(const float4*)&sXT[k][tr * 8];
            float4 xb = *(const float4*)&sXT[k][tr * 8 + 4];
            float4 wv = *(const float4*)&sW[k][tc * 4];
            float xr[8] = {xa.x, xa.y, xa.z, xa.w, xb.x, xb.y, xb.z, xb.w};
            float wr[4] = {wv.x, wv.y, wv.z, wv.w};
#pragma unroll
            for (int i = 0; i < 8; ++i)
#pragma unroll
                for (int jj = 0; jj < 4; ++jj)
                    acc[i][jj] = fmaf(xr[i], wr[jj], acc[i][jj]);
        }
        __syncthreads();
    }
#pragma unroll
    for (int i = 0; i < 8; ++i) {
        int r = row0 + tr * 8 + i;
        if (r < N_NODES)
            *(float4*)(Y + (size_t)r * NHID + tc * 4) =
                make_float4(acc[i][0], acc[i][1], acc[i][2], acc[i][3]);
    }
}

// ---------------- GEMM2: h[N,64] @ W2[64,40] ----------------
__global__ __launch_bounds__(256) void gemm2_k(const float* __restrict__ X, const float* __restrict__ W,
                                               float* __restrict__ Y) {
    __shared__ float sXT[8][128];
    __shared__ float sW[320];
    int tid = threadIdx.x;
    int row0 = blockIdx.x * 128;
    int tc = tid & 7;
    int tr = tid >> 3;
    float acc[4][5] = {};
    int lrow = tid >> 1, lhalf = tid & 1;
    int grow = row0 + lrow;
    for (int k0 = 0; k0 < NHID; k0 += 8) {
        float4 v = make_float4(0.f, 0.f, 0.f, 0.f);
        if (grow < N_NODES) v = *(const float4*)(X + (size_t)grow * NHID + k0 + lhalf * 4);
        sXT[lhalf * 4 + 0][lrow] = v.x;
        sXT[lhalf * 4 + 1][lrow] = v.y;
        sXT[lhalf * 4 + 2][lrow] = v.z;
        sXT[lhalf * 4 + 3][lrow] = v.w;
        if (tid < 160) {
            float2 w2 = *(const float2*)(W + k0 * NCLS + tid * 2);
            sW[tid * 2] = w2.x; sW[tid * 2 + 1] = w2.y;
        }
        __syncthreads();
#pragma unroll
        for (int k = 0; k < 8; ++k) {
            float4 xv = *(const float4*)&sXT[k][tr * 4];
            float xr[4] = {xv.x, xv.y, xv.z, xv.w};
            float wr[5];
#pragma unroll
            for (int jj = 0; jj < 5; ++jj) wr[jj] = sW[k * NCLS + tc * 5 + jj];
#pragma unroll
            for (int i = 0; i < 4; ++i)
#pragma unroll
                for (int jj = 0; jj < 5; ++jj)
                    acc[i][jj] = fmaf(xr[i], wr[jj], acc[i][jj]);
        }
        __syncthreads();
    }
#pragma unroll
    for (int i = 0; i < 4; ++i) {
        int r = row0 + tr * 4 + i;
        if (r < N_NODES) {
#pragma unroll
            for (int jj = 0; jj < 5; ++jj) Y[(size_t)r * NCLS + tc * 5 + jj] = acc[i][jj];
        }
    }
}

// ---------------- aggregation layer 1 (wave per node, branchless unroll-4) ----------------
__global__ __launch_bounds__(256) void agg1_k(const float* __restrict__ hpre, const int* __restrict__ row_start,
                                              const int* __restrict__ csr_src, const float* __restrict__ wsl,
                                              const float* __restrict__ dis, const float* __restrict__ w_s,
                                              const float* __restrict__ b, float* __restrict__ h) {
    int j = (blockIdx.x * 256 + threadIdx.x) >> 6;
    int lane = threadIdx.x & 63;
    if (j >= N_NODES) return;
    int e0 = row_start[j], e1 = row_start[j + 1];
    float acc = 0.f;
    int t = e0;
    for (; t + 4 <= e1; t += 4) {
        int s0 = csr_src[t], s1 = csr_src[t + 1], s2 = csr_src[t + 2], s3 = csr_src[t + 3];
        float w0 = wsl[t], w1 = wsl[t + 1], w2 = wsl[t + 2], w3 = wsl[t + 3];
        float v0 = hpre[(size_t)s0 * NHID + lane];
        float v1 = hpre[(size_t)s1 * NHID + lane];
        float v2 = hpre[(size_t)s2 * NHID + lane];
        float v3 = hpre[(size_t)s3 * NHID + lane];
        acc = fmaf(w0, v0, acc); acc = fmaf(w1, v1, acc);
        acc = fmaf(w2, v2, acc); acc = fmaf(w3, v3, acc);
    }
    for (; t < e1; ++t)
        acc = fmaf(wsl[t], hpre[(size_t)csr_src[t] * NHID + lane], acc);
    float dj = dis[j];
    acc = fmaf(dj * (w_s[j] + 1.f), hpre[(size_t)j * NHID + lane], acc);
    float v = fmaf(acc, dj, b[lane]);
    h[(size_t)j * NHID + lane] = fmaxf(v, 0.f);
}

// ---------------- aggregation layer 2 + log_softmax (wave per node, branchless unroll-4) ----------------
__global__ __launch_bounds__(256) void agg2_k(const float* __restrict__ hp2, const int* __restrict__ row_start,
                                              const int* __restrict__ csr_src, const float* __restrict__ wsl,
                                              const float* __restrict__ dis, const float* __restrict__ w_s,
                                              const float* __restrict__ b, float* __restrict__ out) {
    int j = (blockIdx.x * 256 + threadIdx.x) >> 6;
    int lane = threadIdx.x & 63;
    if (j >= N_NODES) return;
    int lc = (lane < NCLS) ? lane : (NCLS - 1);   // clamped gather lane (same cachelines)
    int e0 = row_start[j], e1 = row_start[j + 1];
    float acc = 0.f;
    int t = e0;
    for (; t + 4 <= e1; t += 4) {
        int s0 = csr_src[t], s1 = csr_src[t + 1], s2 = csr_src[t + 2], s3 = csr_src[t + 3];
        float w0 = wsl[t], w1 = wsl[t + 1], w2 = wsl[t + 2], w3 = wsl[t + 3];
        float v0 = hp2[(size_t)s0 * NCLS + lc];
        float v1 = hp2[(size_t)s1 * NCLS + lc];
        float v2 = hp2[(size_t)s2 * NCLS + lc];
        float v3 = hp2[(size_t)s3 * NCLS + lc];
        acc = fmaf(w0, v0, acc); acc = fmaf(w1, v1, acc);
        acc = fmaf(w2, v2, acc); acc = fmaf(w3, v3, acc);
    }
    for (; t < e1; ++t)
        acc = fmaf(wsl[t], hp2[(size_t)csr_src[t] * NCLS + lc], acc);
    float dj = dis[j];
    acc = fmaf(dj * (w_s[j] + 1.f), hp2[(size_t)j * NCLS + lc], acc);
    float v = (lane < NCLS) ? fmaf(acc, dj, b[lane]) : -1e30f;
    float m = v;
#pragma unroll
    for (int off = 32; off; off >>= 1) m = fmaxf(m, __shfl_xor(m, off));
    float ex = (lane < NCLS) ? expf(v - m) : 0.f;
    float ssum = ex;
#pragma unroll
    for (int off = 32; off; off >>= 1) ssum += __shfl_xor(ssum, off);
    if (lane < NCLS) out[(size_t)j * NCLS + lane] = v - m - logf(ssum);
}

extern "C" void kernel_launch(void* const* d_in, const int* in_sizes, int n_in,
                              void* d_out, int out_size, void* d_ws, size_t ws_size,
                              hipStream_t stream) {
    (void)in_sizes; (void)n_in; (void)out_size; (void)ws_size;
    const float* x  = (const float*)d_in[0];
    const int*   src = (const int*)d_in[1];
    const int*   dst = (const int*)d_in[2];
    const int*   rev = (const int*)d_in[3];
    const float* W1 = (const float*)d_in[4];
    const float* b1 = (const float*)d_in[5];
    const float* W2 = (const float*)d_in[6];
    const float* b2 = (const float*)d_in[7];
    const float* Wd = (const float*)d_in[8];
    const float* bd = (const float*)d_in[9];
    float* out = (float*)d_out;

    char* ws = (char*)d_ws;
    size_t off = 0;
    auto alloc = [&](size_t bytes) -> void* {
        void* p = ws + off;
        off = (off + bytes + 255) & ~(size_t)255;
        return p;
    };
    size_t zg0 = off;
    float* rowsum = (float*)alloc((size_t)N_NODES * 4);
    float* deg    = (float*)alloc((size_t)N_NODES * 4);
    float* degc   = (float*)alloc((size_t)N_NODES * 4);
    size_t zg0_end = off;            // pass-2 re-zero: rowsum..degc
    int*   cnt    = (int*)alloc((size_t)N_NODES * 4);   // doubles as cursor
    size_t zg1_end = off;            // initial zero: rowsum..cnt
    float* nrm  = (float*)alloc((size_t)N_NODES * 4);
    float* w_s  = (float*)alloc((size_t)N_NODES * 4);
    float* dis  = (float*)alloc((size_t)N_NODES * 4);
    float* sbuf = (float*)alloc((size_t)E_TOT * 4);     // raw masked sim values
    float* we1  = (float*)alloc((size_t)E_TOT * 4);
    float* we2  = (float*)alloc((size_t)E_TOT * 4);
    float* wsl  = (float*)alloc((size_t)E_TOT * 4);
    float* hpre = (float*)alloc((size_t)N_NODES * NHID * 4);
    float* h    = (float*)alloc((size_t)N_NODES * NHID * 4);
    int* row_start = (int*)alloc((size_t)(N_NODES + 1) * 4);
    int* csr_src   = (int*)alloc((size_t)E_TOT * 4);
    int* csr_eid   = (int*)alloc((size_t)E_TOT * 4);
    int* bsum      = (int*)alloc(256 * 4);

    const int BE = (E_TOT + 255) / 256;
    const int BN = (N_NODES + 255) / 256;
    const int BW = (N_NODES * 64 + 255) / 256;
    const int BS = (E_HALF * 16 + 255) / 256;
    const int BG = (N_NODES + 127) / 128;

    hipMemsetAsync(ws + zg0, 0, zg1_end - zg0, stream);   // rowsum,deg,degc,cnt

    // CSR (topology shared by both layers)
    count_k<<<BE, 256, 0, stream>>>(dst, cnt);
    scan1_k<<<SCAN_NB, 1024, 0, stream>>>(cnt, bsum);
    scan2_k<<<1, 128, 0, stream>>>(bsum);
    scan3_k<<<SCAN_NB, 1024, 0, stream>>>(cnt, bsum, row_start);
    hipMemsetAsync(cnt, 0, (size_t)N_NODES * 4, stream);  // reuse as cursor
    fill_k<<<BE, 256, 0, stream>>>(src, dst, row_start, cnt, csr_src, csr_eid);

    // ---- pass 1: attention on raw features ----
    row_norm_k<NFEAT><<<BW, 256, 0, stream>>>(x, nrm);
    sim_k<NFEAT, false><<<BS, 256, 0, stream>>>(x, nrm, src, dst, rev, nullptr, sbuf, rowsum);
    keep_k<<<BE, 256, 0, stream>>>(sbuf, rev, src, dst, rowsum, Wd, bd, we1, deg, degc);
    node_k<<<BN, 256, 0, stream>>>(deg, w_s, degc, dis);
    gemm1_k<<<BG, 256, 0, stream>>>(x, W1, hpre);
    slotw_k<<<BE, 256, 0, stream>>>(csr_src, csr_eid, we1, dis, wsl);
    agg1_k<<<BW, 256, 0, stream>>>(hpre, row_start, csr_src, wsl, dis, w_s, b1, h);

    // ---- pass 2: attention on hidden features ----
    hipMemsetAsync(ws + zg0, 0, zg0_end - zg0, stream);   // rowsum,deg,degc
    row_norm_k<NHID><<<BW, 256, 0, stream>>>(h, nrm);
    sim_k<NHID, true><<<BS, 256, 0, stream>>>(h, nrm, src, dst, rev, we1, sbuf, rowsum);
    keep_k<<<BE, 256, 0, stream>>>(sbuf, rev, src, dst, rowsum, Wd, bd, we2, deg, degc);
    node_k<<<BN, 256, 0, stream>>>(deg, w_s, degc, dis);
    gemm2_k<<<BG, 256, 0, stream>>>(h, W2, hpre);         // hpre reused as [N,40]
    slotw_k<<<BE, 256, 0, stream>>>(csr_src, csr_eid, we2, dis, wsl);
    agg2_k<<<BW, 256, 0, stream>>>(hpre, row_start, csr_src, wsl, dis, w_s, b2, out);
}

// Round 3
// 609.262 us; speedup vs baseline: 1.5939x; 1.2944x over previous
//
#include <hip/hip_runtime.h>

#define N_NODES 100000
#define E_HALF  500000
#define E_TOT   1000000
#define NFEAT   128
#define NHID    64
#define NCLS    40
#define SCAN_T  1024
#define SCAN_NB 98   // ceil(N_NODES/1024)

// rev is arithmetic by construction: rev = concat(arange+E_HALF, arange)
__device__ __forceinline__ int REV(int e) { return (e < E_HALF) ? e + E_HALF : e - E_HALF; }

// ---------------- node norms ----------------
template<int D>
__global__ __launch_bounds__(256) void row_norm_k(const float* __restrict__ x, float* __restrict__ nrm) {
    int w = (blockIdx.x * 256 + threadIdx.x) >> 6;
    int lane = threadIdx.x & 63;
    if (w >= N_NODES) return;
    const float* row = x + (size_t)w * D;
    float s = 0.f;
#pragma unroll
    for (int i = 0; i < D / 64; ++i) { float v = row[lane + 64 * i]; s = fmaf(v, v, s); }
#pragma unroll
    for (int off = 32; off; off >>= 1) s += __shfl_xor(s, off);
    if (lane == 0) nrm[w] = sqrtf(s);
}

// ---------------- cosine sim on edge pairs (16 lanes / undirected pair), no atomics ----------------
template<int D, bool MASKED>
__global__ __launch_bounds__(256) void sim_k(const float* __restrict__ f, const float* __restrict__ nrm,
                                             const int* __restrict__ src, const int* __restrict__ dst,
                                             const float* __restrict__ we_mask,
                                             float* __restrict__ sim) {
    int g = blockIdx.x * 256 + threadIdx.x;
    int ep = g >> 4, sl = g & 15;
    if (ep >= E_HALF) return;
    bool m0 = true, m1 = true;
    if (MASKED) {
        m0 = we_mask[ep] > 0.f;
        m1 = we_mask[ep + E_HALF] > 0.f;
        if (!m0 && !m1) {               // both directions dropped in pass 1: skip the row gathers
            if (sl == 0) { sim[ep] = 0.f; sim[ep + E_HALF] = 0.f; }
            return;
        }
    }
    int s = src[ep], d = dst[ep];
    const float* fa = f + (size_t)s * D + sl * (D / 16);
    const float* fb = f + (size_t)d * D + sl * (D / 16);
    float acc = 0.f;
#pragma unroll
    for (int i = 0; i < D / 16; i += 4) {
        float4 va = *(const float4*)(fa + i);
        float4 vb = *(const float4*)(fb + i);
        acc = fmaf(va.x, vb.x, acc); acc = fmaf(va.y, vb.y, acc);
        acc = fmaf(va.z, vb.z, acc); acc = fmaf(va.w, vb.w, acc);
    }
    acc += __shfl_xor(acc, 8); acc += __shfl_xor(acc, 4);
    acc += __shfl_xor(acc, 2); acc += __shfl_xor(acc, 1);
    if (sl == 0) {
        float na = nrm[s]; na = (na == 0.f) ? 1.f : na;
        float nb = nrm[d]; nb = (nb == 0.f) ? 1.f : nb;
        float c = acc / (na * nb);
        float t = (c < 0.1f) ? 0.f : c;      // t >= 0 always
        sim[ep]          = m0 ? t : 0.f;
        sim[ep + E_HALF] = m1 ? t : 0.f;
    }
}

// ---------------- rowsum[j] = sum of sim over out-edges (CSR row j), 4 lanes/node ----------------
__global__ __launch_bounds__(256) void rowsum_k(const float* __restrict__ sim, const int* __restrict__ row_start,
                                                const int* __restrict__ csr_eid, float* __restrict__ rowsum) {
    int g = blockIdx.x * 256 + threadIdx.x;
    int j = g >> 2, l = g & 3;
    if (j >= N_NODES) return;
    int e0 = row_start[j], e1 = row_start[j + 1];
    float s = 0.f;
    for (int t = e0 + l; t < e1; t += 4) s += sim[csr_eid[t]];
    s += __shfl_xor(s, 1); s += __shfl_xor(s, 2);
    if (l == 0) rowsum[j] = s;
}

// ---------------- fused L1-normalize + learnable keep/drop -> w_e (pure streaming) ----------------
__global__ __launch_bounds__(256) void keep_k(const float* __restrict__ sim,
                                              const int* __restrict__ src, const int* __restrict__ dst,
                                              const float* __restrict__ rowsum,
                                              const float* __restrict__ Wd, const float* __restrict__ bd,
                                              float* __restrict__ we) {
    int e = blockIdx.x * 256 + threadIdx.x;
    if (e >= E_TOT) return;
    int s = src[e], d = dst[e];
    float rs = rowsum[s]; rs = (rs == 0.f) ? 1.f : rs;
    float rd = rowsum[d]; rd = (rd == 0.f) ? 1.f : rd;      // src[rev[e]] == dst[e]
    float ae = sim[e] / rs;
    float ar = sim[REV(e)] / rd;
    float z = ae * Wd[0] + ar * Wd[1] + bd[0];
    float av = (z > 0.f) ? ae : 0.f;          // sigmoid(z)>0.5 <=> z>0
    we[e] = (av > 0.f) ? expf(av) : 0.f;
}

// ---------------- per-node: deg (surviving out-edges), degc (in-weight sum) -> w_s, dis ----------------
__global__ __launch_bounds__(256) void nodeB_k(const float* __restrict__ we, const int* __restrict__ row_start,
                                               const int* __restrict__ csr_eid,
                                               float* __restrict__ w_s, float* __restrict__ dis) {
    int g = blockIdx.x * 256 + threadIdx.x;
    int j = g >> 2, l = g & 3;
    if (j >= N_NODES) return;
    int e0 = row_start[j], e1 = row_start[j + 1];
    float c = 0.f, s = 0.f;
    for (int t = e0 + l; t < e1; t += 4) {
        int eid = csr_eid[t];
        c += (we[eid] > 0.f) ? 1.f : 0.f;   // deg: surviving out-edges
        s += we[REV(eid)];                  // degc: surviving in-edge weights
    }
    c += __shfl_xor(c, 1); c += __shfl_xor(c, 2);
    s += __shfl_xor(s, 1); s += __shfl_xor(s, 2);
    if (l == 0) {
        float ws = expf(1.f / (c + 1.f));
        w_s[j] = ws;
        dis[j] = 1.f / sqrtf(s + ws + 1.f);
    }
}

// ---------------- CSR build (by src) ----------------
__global__ __launch_bounds__(256) void count_k(const int* __restrict__ src, int* __restrict__ cnt) {
    int e = blockIdx.x * 256 + threadIdx.x;
    if (e < E_TOT) atomicAdd(&cnt[src[e]], 1);
}

__global__ __launch_bounds__(1024) void scan1_k(const int* __restrict__ cnt, int* __restrict__ bsum) {
    int i = blockIdx.x * SCAN_T + threadIdx.x;
    int v = (i < N_NODES) ? cnt[i] : 0;
#pragma unroll
    for (int off = 32; off; off >>= 1) v += __shfl_xor(v, off);
    __shared__ int wsm[16];
    int lane = threadIdx.x & 63, wid = threadIdx.x >> 6;
    if (lane == 0) wsm[wid] = v;
    __syncthreads();
    if (threadIdx.x == 0) {
        int s = 0;
#pragma unroll
        for (int k = 0; k < 16; ++k) s += wsm[k];
        bsum[blockIdx.x] = s;
    }
}

__global__ __launch_bounds__(128) void scan2_k(int* __restrict__ bsum) {
    __shared__ int tmp[128];
    int t = threadIdx.x;
    int v = (t < SCAN_NB) ? bsum[t] : 0;
    tmp[t] = v;
    __syncthreads();
    for (int off = 1; off < 128; off <<= 1) {
        int add = (t >= off) ? tmp[t - off] : 0;
        __syncthreads();
        tmp[t] += add;
        __syncthreads();
    }
    if (t < SCAN_NB) bsum[t] = (t > 0) ? tmp[t - 1] : 0;
}

__global__ __launch_bounds__(1024) void scan3_k(const int* __restrict__ cnt, const int* __restrict__ bsum,
                                                int* __restrict__ row_start) {
    int i = blockIdx.x * SCAN_T + threadIdx.x;
    int v = (i < N_NODES) ? cnt[i] : 0;
    int lane = threadIdx.x & 63, wid = threadIdx.x >> 6;
    int x = v;
#pragma unroll
    for (int off = 1; off < 64; off <<= 1) {
        int y = __shfl_up(x, off);
        if (lane >= off) x += y;
    }
    __shared__ int wsum[16], woff[16];
    if (lane == 63) wsum[wid] = x;
    __syncthreads();
    if (threadIdx.x == 0) {
        int s = 0;
#pragma unroll
        for (int k = 0; k < 16; ++k) { woff[k] = s; s += wsum[k]; }
    }
    __syncthreads();
    int excl = (x - v) + woff[wid] + bsum[blockIdx.x];
    if (i < N_NODES) row_start[i] = excl;
    if (i == N_NODES - 1) row_start[N_NODES] = excl + v;
}

__global__ __launch_bounds__(256) void fill_k(const int* __restrict__ src, const int* __restrict__ dst,
                                              const int* __restrict__ row_start, int* __restrict__ cursor,
                                              int* __restrict__ csr_col, int* __restrict__ csr_eid) {
    int e = blockIdx.x * 256 + threadIdx.x;
    if (e >= E_TOT) return;
    int s = src[e];
    int p = atomicAdd(&cursor[s], 1);
    int slot = row_start[s] + p;
    csr_col[slot] = dst[e];
    csr_eid[slot] = e;
}

// ---------------- per-slot weight = dis[col] * w_e[REV(eid)] (in-edge weight) ----------------
__global__ __launch_bounds__(256) void slotw_k(const int* __restrict__ csr_col, const int* __restrict__ csr_eid,
                                               const float* __restrict__ we, const float* __restrict__ dis,
                                               float* __restrict__ wsl) {
    int t = blockIdx.x * 256 + threadIdx.x;
    if (t >= E_TOT) return;
    wsl[t] = dis[csr_col[t]] * we[REV(csr_eid[t])];
}

// ---------------- GEMM1: x[N,128] @ W1[128,64] ----------------
__global__ __launch_bounds__(256) void gemm1_k(const float* __restrict__ X, const float* __restrict__ W,
                                               float* __restrict__ Y) {
    __shared__ float sXT[8][128];
    __shared__ float sW[8][64];
    int tid = threadIdx.x;
    int row0 = blockIdx.x * 128;
    int tc = tid & 15;
    int tr = tid >> 4;
    float acc[8][4] = {};
    int lrow = tid >> 1, lhalf = tid & 1;
    int grow = row0 + lrow;
    for (int k0 = 0; k0 < NFEAT; k0 += 8) {
        float4 v = make_float4(0.f, 0.f, 0.f, 0.f);
        if (grow < N_NODES) v = *(const float4*)(X + (size_t)grow * NFEAT + k0 + lhalf * 4);
        sXT[lhalf * 4 + 0][lrow] = v.x;
        sXT[lhalf * 4 + 1][lrow] = v.y;
        sXT[lhalf * 4 + 2][lrow] = v.z;
        sXT[lhalf * 4 + 3][lrow] = v.w;
        float2 wv2 = *(const float2*)(W + (size_t)(k0 + (tid >> 5)) * NHID + (tid & 31) * 2);
        *(float2*)&sW[tid >> 5][(tid & 31) * 2] = wv2;
        __syncthreads();
#pragma unroll
        for (int k = 0; k < 8; ++k) {
            float4 xa = *(const float4*)&sXT[k][tr * 8];
            float4 xb = *(const float4*)&sXT[k][tr * 8 + 4];
            float4 wv = *(const float4*)&sW[k][tc * 4];
            float xr[8] = {xa.x, xa.y, xa.z, xa.w, xb.x, xb.y, xb.z, xb.w};
            float wr[4] = {wv.x, wv.y, wv.z, wv.w};
#pragma unroll
            for (int i = 0; i < 8; ++i)
#pragma unroll
                for (int jj = 0; jj < 4; ++jj)
                    acc[i][jj] = fmaf(xr[i], wr[jj], acc[i][jj]);
        }
        __syncthreads();
    }
#pragma unroll
    for (int i = 0; i < 8; ++i) {
        int r = row0 + tr * 8 + i;
        if (r < N_NODES)
            *(float4*)(Y + (size_t)r * NHID + tc * 4) =
                make_float4(acc[i][0], acc[i][1], acc[i][2], acc[i][3]);
    }
}

// ---------------- GEMM2: h[N,64] @ W2[64,40] ----------------
__global__ __launch_bounds__(256) void gemm2_k(const float* __restrict__ X, const float* __restrict__ W,
                                               float* __restrict__ Y) {
    __shared__ float sXT[8][128];
    __shared__ float sW[320];
    int tid = threadIdx.x;
    int row0 = blockIdx.x * 128;
    int tc = tid & 7;
    int tr = tid >> 3;
    float acc[4][5] = {};
    int lrow = tid >> 1, lhalf = tid & 1;
    int grow = row0 + lrow;
    for (int k0 = 0; k0 < NHID; k0 += 8) {
        float4 v = make_float4(0.f, 0.f, 0.f, 0.f);
        if (grow < N_NODES) v = *(const float4*)(X + (size_t)grow * NHID + k0 + lhalf * 4);
        sXT[lhalf * 4 + 0][lrow] = v.x;
        sXT[lhalf * 4 + 1][lrow] = v.y;
        sXT[lhalf * 4 + 2][lrow] = v.z;
        sXT[lhalf * 4 + 3][lrow] = v.w;
        if (tid < 160) {
            float2 w2 = *(const float2*)(W + k0 * NCLS + tid * 2);
            sW[tid * 2] = w2.x; sW[tid * 2 + 1] = w2.y;
        }
        __syncthreads();
#pragma unroll
        for (int k = 0; k < 8; ++k) {
            float4 xv = *(const float4*)&sXT[k][tr * 4];
            float xr[4] = {xv.x, xv.y, xv.z, xv.w};
            float wr[5];
#pragma unroll
            for (int jj = 0; jj < 5; ++jj) wr[jj] = sW[k * NCLS + tc * 5 + jj];
#pragma unroll
            for (int i = 0; i < 4; ++i)
#pragma unroll
                for (int jj = 0; jj < 5; ++jj)
                    acc[i][jj] = fmaf(xr[i], wr[jj], acc[i][jj]);
        }
        __syncthreads();
    }
#pragma unroll
    for (int i = 0; i < 4; ++i) {
        int r = row0 + tr * 4 + i;
        if (r < N_NODES) {
#pragma unroll
            for (int jj = 0; jj < 5; ++jj) Y[(size_t)r * NCLS + tc * 5 + jj] = acc[i][jj];
        }
    }
}

// ---------------- aggregation layer 1 (wave per node, branchless unroll-4) ----------------
__global__ __launch_bounds__(256) void agg1_k(const float* __restrict__ hpre, const int* __restrict__ row_start,
                                              const int* __restrict__ csr_col, const float* __restrict__ wsl,
                                              const float* __restrict__ dis, const float* __restrict__ w_s,
                                              const float* __restrict__ b, float* __restrict__ h) {
    int j = (blockIdx.x * 256 + threadIdx.x) >> 6;
    int lane = threadIdx.x & 63;
    if (j >= N_NODES) return;
    int e0 = row_start[j], e1 = row_start[j + 1];
    float acc = 0.f;
    int t = e0;
    for (; t + 4 <= e1; t += 4) {
        int s0 = csr_col[t], s1 = csr_col[t + 1], s2 = csr_col[t + 2], s3 = csr_col[t + 3];
        float w0 = wsl[t], w1 = wsl[t + 1], w2 = wsl[t + 2], w3 = wsl[t + 3];
        float v0 = hpre[(size_t)s0 * NHID + lane];
        float v1 = hpre[(size_t)s1 * NHID + lane];
        float v2 = hpre[(size_t)s2 * NHID + lane];
        float v3 = hpre[(size_t)s3 * NHID + lane];
        acc = fmaf(w0, v0, acc); acc = fmaf(w1, v1, acc);
        acc = fmaf(w2, v2, acc); acc = fmaf(w3, v3, acc);
    }
    for (; t < e1; ++t)
        acc = fmaf(wsl[t], hpre[(size_t)csr_col[t] * NHID + lane], acc);
    float dj = dis[j];
    acc = fmaf(dj * (w_s[j] + 1.f), hpre[(size_t)j * NHID + lane], acc);
    float v = fmaf(acc, dj, b[lane]);
    h[(size_t)j * NHID + lane] = fmaxf(v, 0.f);
}

// ---------------- aggregation layer 2 + log_softmax (wave per node, branchless unroll-4) ----------------
__global__ __launch_bounds__(256) void agg2_k(const float* __restrict__ hp2, const int* __restrict__ row_start,
                                              const int* __restrict__ csr_col, const float* __restrict__ wsl,
                                              const float* __restrict__ dis, const float* __restrict__ w_s,
                                              const float* __restrict__ b, float* __restrict__ out) {
    int j = (blockIdx.x * 256 + threadIdx.x) >> 6;
    int lane = threadIdx.x & 63;
    if (j >= N_NODES) return;
    int lc = (lane < NCLS) ? lane : (NCLS - 1);   // clamped gather lane (same cachelines)
    int e0 = row_start[j], e1 = row_start[j + 1];
    float acc = 0.f;
    int t = e0;
    for (; t + 4 <= e1; t += 4) {
        int s0 = csr_col[t], s1 = csr_col[t + 1], s2 = csr_col[t + 2], s3 = csr_col[t + 3];
        float w0 = wsl[t], w1 = wsl[t + 1], w2 = wsl[t + 2], w3 = wsl[t + 3];
        float v0 = hp2[(size_t)s0 * NCLS + lc];
        float v1 = hp2[(size_t)s1 * NCLS + lc];
        float v2 = hp2[(size_t)s2 * NCLS + lc];
        float v3 = hp2[(size_t)s3 * NCLS + lc];
        acc = fmaf(w0, v0, acc); acc = fmaf(w1, v1, acc);
        acc = fmaf(w2, v2, acc); acc = fmaf(w3, v3, acc);
    }
    for (; t < e1; ++t)
        acc = fmaf(wsl[t], hp2[(size_t)csr_col[t] * NCLS + lc], acc);
    float dj = dis[j];
    acc = fmaf(dj * (w_s[j] + 1.f), hp2[(size_t)j * NCLS + lc], acc);
    float v = (lane < NCLS) ? fmaf(acc, dj, b[lane]) : -1e30f;
    float m = v;
#pragma unroll
    for (int off = 32; off; off >>= 1) m = fmaxf(m, __shfl_xor(m, off));
    float ex = (lane < NCLS) ? expf(v - m) : 0.f;
    float ssum = ex;
#pragma unroll
    for (int off = 32; off; off >>= 1) ssum += __shfl_xor(ssum, off);
    if (lane < NCLS) out[(size_t)j * NCLS + lane] = v - m - logf(ssum);
}

extern "C" void kernel_launch(void* const* d_in, const int* in_sizes, int n_in,
                              void* d_out, int out_size, void* d_ws, size_t ws_size,
                              hipStream_t stream) {
    (void)in_sizes; (void)n_in; (void)out_size; (void)ws_size;
    const float* x  = (const float*)d_in[0];
    const int*   src = (const int*)d_in[1];
    const int*   dst = (const int*)d_in[2];
    const float* W1 = (const float*)d_in[4];
    const float* b1 = (const float*)d_in[5];
    const float* W2 = (const float*)d_in[6];
    const float* b2 = (const float*)d_in[7];
    const float* Wd = (const float*)d_in[8];
    const float* bd = (const float*)d_in[9];
    float* out = (float*)d_out;

    char* ws = (char*)d_ws;
    size_t off = 0;
    auto alloc = [&](size_t bytes) -> void* {
        void* p = ws + off;
        off = (off + bytes + 255) & ~(size_t)255;
        return p;
    };
    int*   cnt    = (int*)alloc((size_t)N_NODES * 4);   // doubles as cursor
    float* nrm    = (float*)alloc((size_t)N_NODES * 4);
    float* rowsum = (float*)alloc((size_t)N_NODES * 4);
    float* w_s    = (float*)alloc((size_t)N_NODES * 4);
    float* dis    = (float*)alloc((size_t)N_NODES * 4);
    float* sbuf   = (float*)alloc((size_t)E_TOT * 4);   // raw masked sim values
    float* we1    = (float*)alloc((size_t)E_TOT * 4);
    float* we2    = (float*)alloc((size_t)E_TOT * 4);
    float* wsl    = (float*)alloc((size_t)E_TOT * 4);
    float* hpre   = (float*)alloc((size_t)N_NODES * NHID * 4);
    float* h      = (float*)alloc((size_t)N_NODES * NHID * 4);
    int* row_start = (int*)alloc((size_t)(N_NODES + 1) * 4);
    int* csr_col   = (int*)alloc((size_t)E_TOT * 4);
    int* csr_eid   = (int*)alloc((size_t)E_TOT * 4);
    int* bsum      = (int*)alloc(256 * 4);

    const int BE = (E_TOT + 255) / 256;
    const int BW = (N_NODES * 64 + 255) / 256;
    const int BQ = (N_NODES * 4 + 255) / 256;
    const int BS = (E_HALF * 16 + 255) / 256;
    const int BG = (N_NODES + 127) / 128;

    // CSR by src (topology shared by both layers; symmetric graph)
    hipMemsetAsync(cnt, 0, (size_t)N_NODES * 4, stream);
    count_k<<<BE, 256, 0, stream>>>(src, cnt);
    scan1_k<<<SCAN_NB, 1024, 0, stream>>>(cnt, bsum);
    scan2_k<<<1, 128, 0, stream>>>(bsum);
    scan3_k<<<SCAN_NB, 1024, 0, stream>>>(cnt, bsum, row_start);
    hipMemsetAsync(cnt, 0, (size_t)N_NODES * 4, stream);  // reuse as cursor
    fill_k<<<BE, 256, 0, stream>>>(src, dst, row_start, cnt, csr_col, csr_eid);

    // ---- pass 1: attention on raw features ----
    row_norm_k<NFEAT><<<BW, 256, 0, stream>>>(x, nrm);
    sim_k<NFEAT, false><<<BS, 256, 0, stream>>>(x, nrm, src, dst, nullptr, sbuf);
    rowsum_k<<<BQ, 256, 0, stream>>>(sbuf, row_start, csr_eid, rowsum);
    keep_k<<<BE, 256, 0, stream>>>(sbuf, src, dst, rowsum, Wd, bd, we1);
    nodeB_k<<<BQ, 256, 0, stream>>>(we1, row_start, csr_eid, w_s, dis);
    gemm1_k<<<BG, 256, 0, stream>>>(x, W1, hpre);
    slotw_k<<<BE, 256, 0, stream>>>(csr_col, csr_eid, we1, dis, wsl);
    agg1_k<<<BW, 256, 0, stream>>>(hpre, row_start, csr_col, wsl, dis, w_s, b1, h);

    // ---- pass 2: attention on hidden features ----
    row_norm_k<NHID><<<BW, 256, 0, stream>>>(h, nrm);
    sim_k<NHID, true><<<BS, 256, 0, stream>>>(h, nrm, src, dst, we1, sbuf);
    rowsum_k<<<BQ, 256, 0, stream>>>(sbuf, row_start, csr_eid, rowsum);
    keep_k<<<BE, 256, 0, stream>>>(sbuf, src, dst, rowsum, Wd, bd, we2);
    nodeB_k<<<BQ, 256, 0, stream>>>(we2, row_start, csr_eid, w_s, dis);
    gemm2_k<<<BG, 256, 0, stream>>>(h, W2, hpre);         // hpre reused as [N,40]
    slotw_k<<<BE, 256, 0, stream>>>(csr_col, csr_eid, we2, dis, wsl);
    agg2_k<<<BW, 256, 0, stream>>>(hpre, row_start, csr_col, wsl, dis, w_s, b2, out);
}

// Round 4
// 591.918 us; speedup vs baseline: 1.6406x; 1.0293x over previous
//
#include <hip/hip_runtime.h>

#define N_NODES 100000
#define E_HALF  500000
#define E_TOT   1000000
#define NFEAT   128
#define NHID    64
#define NCLS    40
#define SCAN_T  1024
#define SCAN_NB 98   // ceil(N_NODES/1024)

// rev is arithmetic by construction: rev = concat(arange+E_HALF, arange)
__device__ __forceinline__ int REV(int e) { return (e < E_HALF) ? e + E_HALF : e - E_HALF; }

// ---------------- node norms (pass-1 only; pass-2 norm fused into agg1) ----------------
template<int D>
__global__ __launch_bounds__(256) void row_norm_k(const float* __restrict__ x, float* __restrict__ nrm) {
    int w = (blockIdx.x * 256 + threadIdx.x) >> 6;
    int lane = threadIdx.x & 63;
    if (w >= N_NODES) return;
    const float* row = x + (size_t)w * D;
    float s = 0.f;
#pragma unroll
    for (int i = 0; i < D / 64; ++i) { float v = row[lane + 64 * i]; s = fmaf(v, v, s); }
#pragma unroll
    for (int off = 32; off; off >>= 1) s += __shfl_xor(s, off);
    if (lane == 0) nrm[w] = sqrtf(s);
}

// ---------------- cosine sim on edge pairs (16 lanes / undirected pair), no atomics ----------------
template<int D, bool MASKED>
__global__ __launch_bounds__(256) void sim_k(const float* __restrict__ f, const float* __restrict__ nrm,
                                             const int* __restrict__ src, const int* __restrict__ dst,
                                             const float* __restrict__ we_mask,
                                             float* __restrict__ sim) {
    int g = blockIdx.x * 256 + threadIdx.x;
    int ep = g >> 4, sl = g & 15;
    if (ep >= E_HALF) return;
    bool m0 = true, m1 = true;
    if (MASKED) {
        m0 = we_mask[ep] > 0.f;
        m1 = we_mask[ep + E_HALF] > 0.f;
        if (!m0 && !m1) {               // both directions dropped in pass 1: skip the row gathers
            if (sl == 0) { sim[ep] = 0.f; sim[ep + E_HALF] = 0.f; }
            return;
        }
    }
    int s = src[ep], d = dst[ep];
    const float* fa = f + (size_t)s * D + sl * (D / 16);
    const float* fb = f + (size_t)d * D + sl * (D / 16);
    float acc = 0.f;
#pragma unroll
    for (int i = 0; i < D / 16; i += 4) {
        float4 va = *(const float4*)(fa + i);
        float4 vb = *(const float4*)(fb + i);
        acc = fmaf(va.x, vb.x, acc); acc = fmaf(va.y, vb.y, acc);
        acc = fmaf(va.z, vb.z, acc); acc = fmaf(va.w, vb.w, acc);
    }
    acc += __shfl_xor(acc, 8); acc += __shfl_xor(acc, 4);
    acc += __shfl_xor(acc, 2); acc += __shfl_xor(acc, 1);
    if (sl == 0) {
        float na = nrm[s]; na = (na == 0.f) ? 1.f : na;
        float nb = nrm[d]; nb = (nb == 0.f) ? 1.f : nb;
        float c = acc / (na * nb);
        float t = (c < 0.1f) ? 0.f : c;      // t >= 0 always
        sim[ep]          = m0 ? t : 0.f;
        sim[ep + E_HALF] = m1 ? t : 0.f;
    }
}

// ---------------- rowsum[j] = sum of sim over out-edges (CSR row j), 4 lanes/node ----------------
__global__ __launch_bounds__(256) void rowsum_k(const float* __restrict__ sim, const int* __restrict__ row_start,
                                                const int2* __restrict__ csr, float* __restrict__ rowsum) {
    int g = blockIdx.x * 256 + threadIdx.x;
    int j = g >> 2, l = g & 3;
    if (j >= N_NODES) return;
    int e0 = row_start[j], e1 = row_start[j + 1];
    float s = 0.f;
    for (int t = e0 + l; t < e1; t += 4) s += sim[csr[t].y];
    s += __shfl_xor(s, 1); s += __shfl_xor(s, 2);
    if (l == 0) rowsum[j] = s;
}

// ---------------- fused L1-normalize + learnable keep/drop -> w_e (pure streaming) ----------------
__global__ __launch_bounds__(256) void keep_k(const float* __restrict__ sim,
                                              const int* __restrict__ src, const int* __restrict__ dst,
                                              const float* __restrict__ rowsum,
                                              const float* __restrict__ Wd, const float* __restrict__ bd,
                                              float* __restrict__ we) {
    int e = blockIdx.x * 256 + threadIdx.x;
    if (e >= E_TOT) return;
    int s = src[e], d = dst[e];
    float rs = rowsum[s]; rs = (rs == 0.f) ? 1.f : rs;
    float rd = rowsum[d]; rd = (rd == 0.f) ? 1.f : rd;      // src[rev[e]] == dst[e]
    float ae = sim[e] / rs;
    float ar = sim[REV(e)] / rd;
    float z = ae * Wd[0] + ar * Wd[1] + bd[0];
    float av = (z > 0.f) ? ae : 0.f;          // sigmoid(z)>0.5 <=> z>0
    we[e] = (av > 0.f) ? expf(av) : 0.f;
}

// ---------------- per-node: deg (surviving out-edges), degc (in-weight sum) -> w_s, dis ----------------
__global__ __launch_bounds__(256) void nodeB_k(const float* __restrict__ we, const int* __restrict__ row_start,
                                               const int2* __restrict__ csr,
                                               float* __restrict__ w_s, float* __restrict__ dis) {
    int g = blockIdx.x * 256 + threadIdx.x;
    int j = g >> 2, l = g & 3;
    if (j >= N_NODES) return;
    int e0 = row_start[j], e1 = row_start[j + 1];
    float c = 0.f, s = 0.f;
    for (int t = e0 + l; t < e1; t += 4) {
        int eid = csr[t].y;
        c += (we[eid] > 0.f) ? 1.f : 0.f;   // deg: surviving out-edges
        s += we[REV(eid)];                  // degc: surviving in-edge weights
    }
    c += __shfl_xor(c, 1); c += __shfl_xor(c, 2);
    s += __shfl_xor(s, 1); s += __shfl_xor(s, 2);
    if (l == 0) {
        float ws = expf(1.f / (c + 1.f));
        w_s[j] = ws;
        dis[j] = 1.f / sqrtf(s + ws + 1.f);
    }
}

// ---------------- CSR build (by src) ----------------
__global__ __launch_bounds__(256) void count_k(const int* __restrict__ src, int* __restrict__ cnt) {
    int e = blockIdx.x * 256 + threadIdx.x;
    if (e < E_TOT) atomicAdd(&cnt[src[e]], 1);
}

__global__ __launch_bounds__(1024) void scan1_k(const int* __restrict__ cnt, int* __restrict__ bsum) {
    int i = blockIdx.x * SCAN_T + threadIdx.x;
    int v = (i < N_NODES) ? cnt[i] : 0;
#pragma unroll
    for (int off = 32; off; off >>= 1) v += __shfl_xor(v, off);
    __shared__ int wsm[16];
    int lane = threadIdx.x & 63, wid = threadIdx.x >> 6;
    if (lane == 0) wsm[wid] = v;
    __syncthreads();
    if (threadIdx.x == 0) {
        int s = 0;
#pragma unroll
        for (int k = 0; k < 16; ++k) s += wsm[k];
        bsum[blockIdx.x] = s;
    }
}

__global__ __launch_bounds__(128) void scan2_k(int* __restrict__ bsum) {
    __shared__ int tmp[128];
    int t = threadIdx.x;
    int v = (t < SCAN_NB) ? bsum[t] : 0;
    tmp[t] = v;
    __syncthreads();
    for (int off = 1; off < 128; off <<= 1) {
        int add = (t >= off) ? tmp[t - off] : 0;
        __syncthreads();
        tmp[t] += add;
        __syncthreads();
    }
    if (t < SCAN_NB) bsum[t] = (t > 0) ? tmp[t - 1] : 0;
}

__global__ __launch_bounds__(1024) void scan3_k(const int* __restrict__ cnt, const int* __restrict__ bsum,
                                                int* __restrict__ row_start) {
    int i = blockIdx.x * SCAN_T + threadIdx.x;
    int v = (i < N_NODES) ? cnt[i] : 0;
    int lane = threadIdx.x & 63, wid = threadIdx.x >> 6;
    int x = v;
#pragma unroll
    for (int off = 1; off < 64; off <<= 1) {
        int y = __shfl_up(x, off);
        if (lane >= off) x += y;
    }
    __shared__ int wsum[16], woff[16];
    if (lane == 63) wsum[wid] = x;
    __syncthreads();
    if (threadIdx.x == 0) {
        int s = 0;
#pragma unroll
        for (int k = 0; k < 16; ++k) { woff[k] = s; s += wsum[k]; }
    }
    __syncthreads();
    int excl = (x - v) + woff[wid] + bsum[blockIdx.x];
    if (i < N_NODES) row_start[i] = excl;
    if (i == N_NODES - 1) row_start[N_NODES] = excl + v;
}

// packed scatter: one 8B store per slot (half the dirty lines of two 4B stores)
__global__ __launch_bounds__(256) void fill_k(const int* __restrict__ src, const int* __restrict__ dst,
                                              const int* __restrict__ row_start, int* __restrict__ cursor,
                                              int2* __restrict__ csr) {
    int e = blockIdx.x * 256 + threadIdx.x;
    if (e >= E_TOT) return;
    int s = src[e];
    int p = atomicAdd(&cursor[s], 1);
    csr[row_start[s] + p] = make_int2(dst[e], e);
}

// ---------------- GEMM1: x[N,128] @ W1[128,64] ----------------
__global__ __launch_bounds__(256) void gemm1_k(const float* __restrict__ X, const float* __restrict__ W,
                                               float* __restrict__ Y) {
    __shared__ float sXT[8][128];
    __shared__ float sW[8][64];
    int tid = threadIdx.x;
    int row0 = blockIdx.x * 128;
    int tc = tid & 15;
    int tr = tid >> 4;
    float acc[8][4] = {};
    int lrow = tid >> 1, lhalf = tid & 1;
    int grow = row0 + lrow;
    for (int k0 = 0; k0 < NFEAT; k0 += 8) {
        float4 v = make_float4(0.f, 0.f, 0.f, 0.f);
        if (grow < N_NODES) v = *(const float4*)(X + (size_t)grow * NFEAT + k0 + lhalf * 4);
        sXT[lhalf * 4 + 0][lrow] = v.x;
        sXT[lhalf * 4 + 1][lrow] = v.y;
        sXT[lhalf * 4 + 2][lrow] = v.z;
        sXT[lhalf * 4 + 3][lrow] = v.w;
        float2 wv2 = *(const float2*)(W + (size_t)(k0 + (tid >> 5)) * NHID + (tid & 31) * 2);
        *(float2*)&sW[tid >> 5][(tid & 31) * 2] = wv2;
        __syncthreads();
#pragma unroll
        for (int k = 0; k < 8; ++k) {
            float4 xa = *(const float4*)&sXT[k][tr * 8];
            float4 xb = *(const float4*)&sXT[k][tr * 8 + 4];
            float4 wv = *(const float4*)&sW[k][tc * 4];
            float xr[8] = {xa.x, xa.y, xa.z, xa.w, xb.x, xb.y, xb.z, xb.w};
            float wr[4] = {wv.x, wv.y, wv.z, wv.w};
#pragma unroll
            for (int i = 0; i < 8; ++i)
#pragma unroll
                for (int jj = 0; jj < 4; ++jj)
                    acc[i][jj] = fmaf(xr[i], wr[jj], acc[i][jj]);
        }
        __syncthreads();
    }
#pragma unroll
    for (int i = 0; i < 8; ++i) {
        int r = row0 + tr * 8 + i;
        if (r < N_NODES)
            *(float4*)(Y + (size_t)r * NHID + tc * 4) =
                make_float4(acc[i][0], acc[i][1], acc[i][2], acc[i][3]);
    }
}

// ---------------- GEMM2: h[N,64] @ W2[64,40] ----------------
__global__ __launch_bounds__(256) void gemm2_k(const float* __restrict__ X, const float* __restrict__ W,
                                               float* __restrict__ Y) {
    __shared__ float sXT[8][128];
    __shared__ float sW[320];
    int tid = threadIdx.x;
    int row0 = blockIdx.x * 128;
    int tc = tid & 7;
    int tr = tid >> 3;
    float acc[4][5] = {};
    int lrow = tid >> 1, lhalf = tid & 1;
    int grow = row0 + lrow;
    for (int k0 = 0; k0 < NHID; k0 += 8) {
        float4 v = make_float4(0.f, 0.f, 0.f, 0.f);
        if (grow < N_NODES) v = *(const float4*)(X + (size_t)grow * NHID + k0 + lhalf * 4);
        sXT[lhalf * 4 + 0][lrow] = v.x;
        sXT[lhalf * 4 + 1][lrow] = v.y;
        sXT[lhalf * 4 + 2][lrow] = v.z;
        sXT[lhalf * 4 + 3][lrow] = v.w;
        if (tid < 160) {
            float2 w2 = *(const float2*)(W + k0 * NCLS + tid * 2);
            sW[tid * 2] = w2.x; sW[tid * 2 + 1] = w2.y;
        }
        __syncthreads();
#pragma unroll
        for (int k = 0; k < 8; ++k) {
            float4 xv = *(const float4*)&sXT[k][tr * 4];
            float xr[4] = {xv.x, xv.y, xv.z, xv.w};
            float wr[5];
#pragma unroll
            for (int jj = 0; jj < 5; ++jj) wr[jj] = sW[k * NCLS + tc * 5 + jj];
#pragma unroll
            for (int i = 0; i < 4; ++i)
#pragma unroll
                for (int jj = 0; jj < 5; ++jj)
                    acc[i][jj] = fmaf(xr[i], wr[jj], acc[i][jj]);
        }
        __syncthreads();
    }
#pragma unroll
    for (int i = 0; i < 4; ++i) {
        int r = row0 + tr * 4 + i;
        if (r < N_NODES) {
#pragma unroll
            for (int jj = 0; jj < 5; ++jj) Y[(size_t)r * NCLS + tc * 5 + jj] = acc[i][jj];
        }
    }
}

// ---------------- aggregation layer 1: inline weights + fused row-norm of h ----------------
__global__ __launch_bounds__(256) void agg1_k(const float* __restrict__ hpre, const int* __restrict__ row_start,
                                              const int2* __restrict__ csr, const float* __restrict__ we,
                                              const float* __restrict__ dis, const float* __restrict__ w_s,
                                              const float* __restrict__ b, float* __restrict__ h,
                                              float* __restrict__ nrm) {
    int j = (blockIdx.x * 256 + threadIdx.x) >> 6;
    int lane = threadIdx.x & 63;
    if (j >= N_NODES) return;
    int e0 = row_start[j], e1 = row_start[j + 1];
    float acc = 0.f;
    int t = e0;
    for (; t + 4 <= e1; t += 4) {
        int2 c0 = csr[t], c1 = csr[t + 1], c2 = csr[t + 2], c3 = csr[t + 3];
        float w0 = dis[c0.x] * we[REV(c0.y)];
        float w1 = dis[c1.x] * we[REV(c1.y)];
        float w2 = dis[c2.x] * we[REV(c2.y)];
        float w3 = dis[c3.x] * we[REV(c3.y)];
        float v0 = hpre[(size_t)c0.x * NHID + lane];
        float v1 = hpre[(size_t)c1.x * NHID + lane];
        float v2 = hpre[(size_t)c2.x * NHID + lane];
        float v3 = hpre[(size_t)c3.x * NHID + lane];
        acc = fmaf(w0, v0, acc); acc = fmaf(w1, v1, acc);
        acc = fmaf(w2, v2, acc); acc = fmaf(w3, v3, acc);
    }
    for (; t < e1; ++t) {
        int2 c = csr[t];
        acc = fmaf(dis[c.x] * we[REV(c.y)], hpre[(size_t)c.x * NHID + lane], acc);
    }
    float dj = dis[j];
    acc = fmaf(dj * (w_s[j] + 1.f), hpre[(size_t)j * NHID + lane], acc);
    float v = fmaxf(fmaf(acc, dj, b[lane]), 0.f);
    h[(size_t)j * NHID + lane] = v;
    float s = v * v;                         // fused row_norm for pass 2
#pragma unroll
    for (int off = 32; off; off >>= 1) s += __shfl_xor(s, off);
    if (lane == 0) nrm[j] = sqrtf(s);
}

// ---------------- aggregation layer 2 + log_softmax ----------------
__global__ __launch_bounds__(256) void agg2_k(const float* __restrict__ hp2, const int* __restrict__ row_start,
                                              const int2* __restrict__ csr, const float* __restrict__ we,
                                              const float* __restrict__ dis, const float* __restrict__ w_s,
                                              const float* __restrict__ b, float* __restrict__ out) {
    int j = (blockIdx.x * 256 + threadIdx.x) >> 6;
    int lane = threadIdx.x & 63;
    if (j >= N_NODES) return;
    int lc = (lane < NCLS) ? lane : (NCLS - 1);   // clamped gather lane (same cachelines)
    int e0 = row_start[j], e1 = row_start[j + 1];
    float acc = 0.f;
    int t = e0;
    for (; t + 4 <= e1; t += 4) {
        int2 c0 = csr[t], c1 = csr[t + 1], c2 = csr[t + 2], c3 = csr[t + 3];
        float w0 = dis[c0.x] * we[REV(c0.y)];
        float w1 = dis[c1.x] * we[REV(c1.y)];
        float w2 = dis[c2.x] * we[REV(c2.y)];
        float w3 = dis[c3.x] * we[REV(c3.y)];
        float v0 = hp2[(size_t)c0.x * NCLS + lc];
        float v1 = hp2[(size_t)c1.x * NCLS + lc];
        float v2 = hp2[(size_t)c2.x * NCLS + lc];
        float v3 = hp2[(size_t)c3.x * NCLS + lc];
        acc = fmaf(w0, v0, acc); acc = fmaf(w1, v1, acc);
        acc = fmaf(w2, v2, acc); acc = fmaf(w3, v3, acc);
    }
    for (; t < e1; ++t) {
        int2 c = csr[t];
        acc = fmaf(dis[c.x] * we[REV(c.y)], hp2[(size_t)c.x * NCLS + lc], acc);
    }
    float dj = dis[j];
    acc = fmaf(dj * (w_s[j] + 1.f), hp2[(size_t)j * NCLS + lc], acc);
    float v = (lane < NCLS) ? fmaf(acc, dj, b[lane]) : -1e30f;
    float m = v;
#pragma unroll
    for (int off = 32; off; off >>= 1) m = fmaxf(m, __shfl_xor(m, off));
    float ex = (lane < NCLS) ? expf(v - m) : 0.f;
    float ssum = ex;
#pragma unroll
    for (int off = 32; off; off >>= 1) ssum += __shfl_xor(ssum, off);
    if (lane < NCLS) out[(size_t)j * NCLS + lane] = v - m - logf(ssum);
}

extern "C" void kernel_launch(void* const* d_in, const int* in_sizes, int n_in,
                              void* d_out, int out_size, void* d_ws, size_t ws_size,
                              hipStream_t stream) {
    (void)in_sizes; (void)n_in; (void)out_size; (void)ws_size;
    const float* x  = (const float*)d_in[0];
    const int*   src = (const int*)d_in[1];
    const int*   dst = (const int*)d_in[2];
    const float* W1 = (const float*)d_in[4];
    const float* b1 = (const float*)d_in[5];
    const float* W2 = (const float*)d_in[6];
    const float* b2 = (const float*)d_in[7];
    const float* Wd = (const float*)d_in[8];
    const float* bd = (const float*)d_in[9];
    float* out = (float*)d_out;

    char* ws = (char*)d_ws;
    size_t off = 0;
    auto alloc = [&](size_t bytes) -> void* {
        void* p = ws + off;
        off = (off + bytes + 255) & ~(size_t)255;
        return p;
    };
    int*   cnt    = (int*)alloc((size_t)N_NODES * 4);   // doubles as cursor
    float* nrm    = (float*)alloc((size_t)N_NODES * 4);
    float* rowsum = (float*)alloc((size_t)N_NODES * 4);
    float* w_s    = (float*)alloc((size_t)N_NODES * 4);
    float* dis    = (float*)alloc((size_t)N_NODES * 4);
    float* sbuf   = (float*)alloc((size_t)E_TOT * 4);   // raw masked sim values
    float* we1    = (float*)alloc((size_t)E_TOT * 4);
    float* we2    = (float*)alloc((size_t)E_TOT * 4);
    float* hpre   = (float*)alloc((size_t)N_NODES * NHID * 4);
    float* h      = (float*)alloc((size_t)N_NODES * NHID * 4);
    int*  row_start = (int*)alloc((size_t)(N_NODES + 1) * 4);
    int2* csr       = (int2*)alloc((size_t)E_TOT * 8);
    int*  bsum      = (int*)alloc(256 * 4);

    const int BE = (E_TOT + 255) / 256;
    const int BW = (N_NODES * 64 + 255) / 256;
    const int BQ = (N_NODES * 4 + 255) / 256;
    const int BS = (E_HALF * 16 + 255) / 256;
    const int BG = (N_NODES + 127) / 128;

    // CSR by src (topology shared by both layers; symmetric graph)
    hipMemsetAsync(cnt, 0, (size_t)N_NODES * 4, stream);
    count_k<<<BE, 256, 0, stream>>>(src, cnt);
    scan1_k<<<SCAN_NB, 1024, 0, stream>>>(cnt, bsum);
    scan2_k<<<1, 128, 0, stream>>>(bsum);
    scan3_k<<<SCAN_NB, 1024, 0, stream>>>(cnt, bsum, row_start);
    hipMemsetAsync(cnt, 0, (size_t)N_NODES * 4, stream);  // reuse as cursor
    fill_k<<<BE, 256, 0, stream>>>(src, dst, row_start, cnt, csr);

    // ---- pass 1: attention on raw features ----
    row_norm_k<NFEAT><<<BW, 256, 0, stream>>>(x, nrm);
    sim_k<NFEAT, false><<<BS, 256, 0, stream>>>(x, nrm, src, dst, nullptr, sbuf);
    rowsum_k<<<BQ, 256, 0, stream>>>(sbuf, row_start, csr, rowsum);
    keep_k<<<BE, 256, 0, stream>>>(sbuf, src, dst, rowsum, Wd, bd, we1);
    nodeB_k<<<BQ, 256, 0, stream>>>(we1, row_start, csr, w_s, dis);
    gemm1_k<<<BG, 256, 0, stream>>>(x, W1, hpre);
    agg1_k<<<BW, 256, 0, stream>>>(hpre, row_start, csr, we1, dis, w_s, b1, h, nrm);

    // ---- pass 2: attention on hidden features ----
    sim_k<NHID, true><<<BS, 256, 0, stream>>>(h, nrm, src, dst, we1, sbuf);
    rowsum_k<<<BQ, 256, 0, stream>>>(sbuf, row_start, csr, rowsum);
    keep_k<<<BE, 256, 0, stream>>>(sbuf, src, dst, rowsum, Wd, bd, we2);
    nodeB_k<<<BQ, 256, 0, stream>>>(we2, row_start, csr, w_s, dis);
    gemm2_k<<<BG, 256, 0, stream>>>(h, W2, hpre);         // hpre reused as [N,40]
    agg2_k<<<BW, 256, 0, stream>>>(hpre, row_start, csr, we2, dis, w_s, b2, out);
}